// Round 3
// baseline (437.146 us; speedup 1.0000x reference)
//
#include <hip/hip_runtime.h>
#include <math.h>

#define T_TOK 16384
#define D_DIM 4096
#define E_EXP 64

// d_out layout (float32): logits [T,64] | weights [T,2] | indices [T,2] | mask [64,2,T]
#define OFF_W   (T_TOK * E_EXP)
#define OFF_I   (OFF_W + T_TOK * 2)
#define OFF_M   (OFF_I + T_TOK * 2)

#define NCHUNK    64      // K chunks of 64 dims
#define CH_HALVES 4096    // 64x64 f16 per chunk per matrix (frag-major: 8 frags x 512)

typedef _Float16 half8 __attribute__((ext_vector_type(8)));
typedef float    f32x4 __attribute__((ext_vector_type(4)));

// ---------------------------------------------------------------------------
// prep: w [64][4096] fp32 -> ws_hi / ws_lo(x2^11) f16, frag-major per K-chunk.
// frag layout (16x16x32 MFMA): lane = n + 16*q holds B[n][q*8+j], j=0..7.
// half offset = chunk*4096 + (n_tile*2 + s)*512 + (n + 16*q)*8 + j
//   where k_in_chunk = s*32 + q*8 + j, n_tile = exp>>4, n = exp&15.
// ---------------------------------------------------------------------------
__global__ __launch_bounds__(256) void prep_w(const float* __restrict__ w,
                                              _Float16* __restrict__ ws_hi,
                                              _Float16* __restrict__ ws_lo) {
  const int g   = blockIdx.x * 256 + threadIdx.x;  // 0..16383
  const int exp = g >> 8;
  const int kb  = (g & 255) * 16;
  const float* src = w + (size_t)exp * D_DIM + kb;
  float vals[16];
#pragma unroll
  for (int i = 0; i < 4; i++) {
    const float4 f = *(const float4*)(src + i * 4);
    vals[i * 4 + 0] = f.x; vals[i * 4 + 1] = f.y;
    vals[i * 4 + 2] = f.z; vals[i * 4 + 3] = f.w;
  }
  const int n_tile = exp >> 4, nn = exp & 15;
#pragma unroll
  for (int part = 0; part < 2; part++) {
    const int k0 = kb + part * 8;
    const int c = k0 >> 6, rem = k0 & 63;
    const int s = rem >> 5, q = (rem >> 3) & 3;
    const size_t off = (size_t)c * CH_HALVES + (n_tile * 2 + s) * 512 + (nn + 16 * q) * 8;
    half8 hv, lv;
#pragma unroll
    for (int j = 0; j < 8; j++) {
      const float xf = vals[part * 8 + j];
      const _Float16 h = (_Float16)xf;            // RNE
      hv[j] = h;
      lv[j] = (_Float16)((xf - (float)h) * 2048.0f);
    }
    *(half8*)(ws_hi + off) = hv;
    *(half8*)(ws_lo + off) = lv;
  }
}

// ---------------------------------------------------------------------------
// main: 256 blocks x 256 thr. Block = 64 tokens x 64 experts, K=4096.
// Wave wg = tokens [wg*16, wg*16+16) x all 64 experts (4 n-tiles).
// logits = hh + 2^-11*(hl + lh); fused top-2 router via 16-lane butterfly.
// ---------------------------------------------------------------------------
__global__ __launch_bounds__(256, 1) void moe_mfma(
    const float* __restrict__ x, const _Float16* __restrict__ ws_hi,
    const _Float16* __restrict__ ws_lo, const float* __restrict__ bias,
    float* __restrict__ out) {
  __shared__ __align__(16) _Float16 smem[2][4][CH_HALVES];  // [buf][Ahi,Alo,Bhi,Blo]

  const int tid  = threadIdx.x;
  const int wave = tid >> 6;
  const int lane = tid & 63;
  const int tok0 = blockIdx.x * 64;
  const int stok = tid >> 2;      // staging token 0..63
  const int so4  = tid & 3;       // staging oct-quarter

  f32x4 accm[4], accc[4];
#pragma unroll
  for (int t = 0; t < 4; t++) {
    accm[t] = (f32x4){0.f, 0.f, 0.f, 0.f};
    accc[t] = (f32x4){0.f, 0.f, 0.f, 0.f};
  }

  float4 xr[2][4];
  uint4  br[2][4];

  auto loadx = [&](int c, float4* xv) {
    const float* p = x + (size_t)(tok0 + stok) * D_DIM + c * 64 + so4 * 8;
    xv[0] = ((const float4*)p)[0];
    xv[1] = ((const float4*)p)[1];
    xv[2] = ((const float4*)(p + 32))[0];
    xv[3] = ((const float4*)(p + 32))[1];
  };
  auto loadB = [&](int c, uint4* bv) {
    const uint4* ph = (const uint4*)(ws_hi + (size_t)c * CH_HALVES) + tid * 2;
    bv[0] = ph[0]; bv[1] = ph[1];
    const uint4* pl = (const uint4*)(ws_lo + (size_t)c * CH_HALVES) + tid * 2;
    bv[2] = pl[0]; bv[3] = pl[1];
  };
  auto stage = [&](int buf, const float4* xv, const uint4* bv) {
    const int g = stok >> 4, m = stok & 15;
#pragma unroll
    for (int p = 0; p < 2; p++) {
      const int o = so4 + 4 * p;       // oct in chunk
      const int s = o >> 2, q = o & 3;
      const int off = (g * 2 + s) * 512 + (m + 16 * q) * 8;
      const float4 f0 = xv[2 * p], f1 = xv[2 * p + 1];
      const float vv[8] = {f0.x, f0.y, f0.z, f0.w, f1.x, f1.y, f1.z, f1.w};
      half8 hv, lv;
#pragma unroll
      for (int j = 0; j < 8; j++) {
        const _Float16 h = (_Float16)vv[j];
        hv[j] = h;
        lv[j] = (_Float16)((vv[j] - (float)h) * 2048.0f);
      }
      *(half8*)(&smem[buf][0][off]) = hv;
      *(half8*)(&smem[buf][1][off]) = lv;
    }
    *(uint4*)(&smem[buf][2][tid * 16])     = bv[0];
    *(uint4*)(&smem[buf][2][tid * 16 + 8]) = bv[1];
    *(uint4*)(&smem[buf][3][tid * 16])     = bv[2];
    *(uint4*)(&smem[buf][3][tid * 16 + 8]) = bv[3];
  };
  auto compute = [&](int buf) {
#pragma unroll
    for (int s = 0; s < 2; s++) {
      const half8 ah = *(const half8*)(&smem[buf][0][(wave * 2 + s) * 512 + lane * 8]);
      const half8 al = *(const half8*)(&smem[buf][1][(wave * 2 + s) * 512 + lane * 8]);
#pragma unroll
      for (int t = 0; t < 4; t++) {
        const half8 bh = *(const half8*)(&smem[buf][2][(t * 2 + s) * 512 + lane * 8]);
        const half8 bl = *(const half8*)(&smem[buf][3][(t * 2 + s) * 512 + lane * 8]);
        accm[t] = __builtin_amdgcn_mfma_f32_16x16x32_f16(ah, bh, accm[t], 0, 0, 0);
        accc[t] = __builtin_amdgcn_mfma_f32_16x16x32_f16(ah, bl, accc[t], 0, 0, 0);
        accc[t] = __builtin_amdgcn_mfma_f32_16x16x32_f16(al, bh, accc[t], 0, 0, 0);
      }
    }
  };

  // ---- software pipeline: double-buffered LDS, 2-deep register prefetch ---
  loadx(0, xr[0]); loadB(0, br[0]);
  stage(0, xr[0], br[0]);
  loadx(1, xr[1]); loadB(1, br[1]);
  __syncthreads();
#pragma unroll 1
  for (int c = 0; c < NCHUNK; c += 2) {
    if (c + 2 < NCHUNK) { loadx(c + 2, xr[0]); loadB(c + 2, br[0]); }
    compute(0);
    stage(1, xr[1], br[1]);
    __syncthreads();
    if (c + 3 < NCHUNK) { loadx(c + 3, xr[1]); loadB(c + 3, br[1]); }
    compute(1);
    if (c + 2 < NCHUNK) stage(0, xr[0], br[0]);
    __syncthreads();
  }

  // ---- epilogue: combine, bias, write logits ----------------------------
  // C/D layout: col = lane&15 (expert-within-tile), row = (lane>>4)*4 + reg (token)
  const int cc = lane & 15, q = lane >> 4;
  float fin[4][4];
#pragma unroll
  for (int t = 0; t < 4; t++) {
    const float bb = bias[t * 16 + cc];
#pragma unroll
    for (int r = 0; r < 4; r++)
      fin[t][r] = accm[t][r] + accc[t][r] * 4.8828125e-4f + bb;  // 2^-11
  }
#pragma unroll
  for (int r = 0; r < 4; r++) {
    const int trow = tok0 + wave * 16 + q * 4 + r;
#pragma unroll
    for (int t = 0; t < 4; t++)
      out[(size_t)trow * E_EXP + t * 16 + cc] = fin[t][r];
  }

  // ---- fused router: top-2 across 16 lanes (butterfly), then write ------
#pragma unroll
  for (int r = 0; r < 4; r++) {
    float v1 = fin[0][r]; int i1 = cc;
    float v2 = -3.4e38f;  int i2 = 0;
#pragma unroll
    for (int t = 1; t < 4; t++) {
      const float vc = fin[t][r]; const int ic = t * 16 + cc;
      if (vc > v1)      { v2 = v1; i2 = i1; v1 = vc; i1 = ic; }
      else if (vc > v2) { v2 = vc; i2 = ic; }
    }
#pragma unroll
    for (int mk = 1; mk <= 8; mk <<= 1) {
      const float ov1 = __shfl_xor(v1, mk); const int oi1 = __shfl_xor(i1, mk);
      const float ov2 = __shfl_xor(v2, mk); const int oi2 = __shfl_xor(i2, mk);
      if ((ov1 > v1) || (ov1 == v1 && oi1 < i1)) {
        const bool s2 = (v1 > ov2) || (v1 == ov2 && i1 < oi2);
        v2 = s2 ? v1 : ov2; i2 = s2 ? i1 : oi2;
        v1 = ov1; i1 = oi1;
      } else {
        const bool s2 = (ov1 > v2) || (ov1 == v2 && oi1 < i2);
        v2 = s2 ? ov1 : v2; i2 = s2 ? oi1 : i2;
      }
    }
    if (cc == 0) {
      const int trow = tok0 + wave * 16 + q * 4 + r;
      const float d  = expf(v2 - v1);
      const float w1 = 1.f / (1.f + d);
      out[OFF_W + trow * 2 + 0] = w1;
      out[OFF_W + trow * 2 + 1] = d * w1;
      out[OFF_I + trow * 2 + 0] = (float)i1;
      out[OFF_I + trow * 2 + 1] = (float)i2;
      out[OFF_M + (size_t)(i1 * 2 + 0) * T_TOK + trow] = 1.0f;
      out[OFF_M + (size_t)(i2 * 2 + 1) * T_TOK + trow] = 1.0f;
    }
  }
}

extern "C" void kernel_launch(void* const* d_in, const int* in_sizes, int n_in,
                              void* d_out, int out_size, void* d_ws, size_t ws_size,
                              hipStream_t stream) {
  const float* x    = (const float*)d_in[0];
  const float* w    = (const float*)d_in[1];
  const float* bias = (const float*)d_in[2];
  float* out = (float*)d_out;
  _Float16* ws_hi = (_Float16*)d_ws;
  _Float16* ws_lo = ws_hi + (size_t)NCHUNK * CH_HALVES;  // +512 KB

  hipMemsetAsync(out + OFF_M, 0, (size_t)E_EXP * 2 * T_TOK * sizeof(float), stream);
  prep_w<<<E_EXP * D_DIM / (256 * 16), 256, 0, stream>>>(w, ws_hi, ws_lo);
  moe_mfma<<<T_TOK / 64, 256, 0, stream>>>(x, ws_hi, ws_lo, bias, out);
}